// Round 1
// baseline (124.766 us; speedup 1.0000x reference)
//
#include <hip/hip_runtime.h>

#define B_DIM   16384
#define T_DIM   50
#define F_DIM   128
#define NSPLIT  63
#define LEAVES  64
#define DEPTHM1 6

#define BPB     10            // b values per block
#define BLOCK   512           // 10*50 = 500 active threads
#define PI_LDA  130           // 128 padded +2 to break bank conflicts across t
#define PROB_SZ (B_DIM * T_DIM * 2)

// Kernel 1: extract gather index + mask value per (t, n) from the one-hot masks.
__global__ void build_tables(const float* __restrict__ masks,
                             int* __restrict__ idx, float* __restrict__ val) {
    int k = blockIdx.x * blockDim.x + threadIdx.x;
    if (k >= T_DIM * NSPLIT) return;
    int t = k / NSPLIT, n = k % NSPLIT;
    int fi = 0; float fv = 0.f;
    for (int f = 0; f < F_DIM; ++f) {
        float m = masks[(t * F_DIM + f) * NSPLIT + n];
        if (m != 0.f) { fi = f; fv = m; }
    }
    idx[k] = fi;
    val[k] = fv;
}

__global__ __launch_bounds__(BLOCK)
void forest_kernel(const float* __restrict__ x, const float* __restrict__ pi,
                   const int* __restrict__ idx, const float* __restrict__ val,
                   float* __restrict__ out) {
    __shared__ float xs[BPB * F_DIM];          //  5.0 KB
    __shared__ int   idx_l[T_DIM * NSPLIT];    // 12.6 KB
    __shared__ float val_l[T_DIM * NSPLIT];    // 12.6 KB
    __shared__ float pi_l[T_DIM * PI_LDA];     // 26.0 KB

    const int tid = threadIdx.x;
    const int b0  = blockIdx.x * BPB;

    // cooperative staging
    for (int i = tid; i < T_DIM * NSPLIT; i += BLOCK) {
        idx_l[i] = idx[i];
        val_l[i] = val[i];
    }
    for (int i = tid; i < T_DIM * F_DIM; i += BLOCK) {
        int t = i / F_DIM, r = i % F_DIM;
        pi_l[t * PI_LDA + r] = pi[i];
    }
    for (int i = tid; i < BPB * F_DIM; i += BLOCK) {
        int bb = i / F_DIM;
        int b  = b0 + bb;
        xs[i] = (b < B_DIM) ? x[b * F_DIM + (i % F_DIM)] : 0.f;
    }
    __syncthreads();

    const int bsub = tid / T_DIM;
    const int t    = tid % T_DIM;
    const int b    = b0 + bsub;
    if (bsub >= BPB || b >= B_DIM) return;

    const int tbase = t * NSPLIT;
    const int xbase = bsub * F_DIM;

    // tree: mu[64] fully static-indexed -> stays in VGPRs
    float mu[LEAVES];
    mu[0] = 1.f;
    int begin = 0;
#pragma unroll
    for (int level = 0; level < DEPTHM1; ++level) {
        const int width = 1 << level;
#pragma unroll
        for (int i = width - 1; i >= 0; --i) {
            const int k = begin + i;
            float xv = xs[xbase + idx_l[tbase + k]] * val_l[tbase + k];
            float d  = 1.f / (1.f + __expf(-xv));
            float m  = mu[i];
            mu[2 * i]     = m * d;
            mu[2 * i + 1] = m * (1.f - d);
        }
        begin += width;
    }

    // prob[b,t,s] = sum_l mu[l] * pi[t,l,s]
    float p0 = 0.f, p1 = 0.f;
    const float* pit = &pi_l[t * PI_LDA];
#pragma unroll
    for (int l = 0; l < LEAVES; ++l) {
        p0 += mu[l] * pit[2 * l];
        p1 += mu[l] * pit[2 * l + 1];
    }
    out[(b * T_DIM + t) * 2 + 0] = p0;
    out[(b * T_DIM + t) * 2 + 1] = p1;

    // probs[b,l,t] = mu[l]; lanes vary in t -> contiguous 50-float runs per store
    float* pr = out + PROB_SZ + (size_t)b * (LEAVES * T_DIM) + t;
#pragma unroll
    for (int l = 0; l < LEAVES; ++l) {
        pr[l * T_DIM] = mu[l];
    }
}

extern "C" void kernel_launch(void* const* d_in, const int* in_sizes, int n_in,
                              void* d_out, int out_size, void* d_ws, size_t ws_size,
                              hipStream_t stream) {
    const float* x     = (const float*)d_in[0];
    const float* masks = (const float*)d_in[1];
    const float* pi    = (const float*)d_in[2];
    // d_in[3] = depth (constant 7, baked in)

    int*   idx = (int*)d_ws;
    float* val = (float*)((char*)d_ws + (size_t)T_DIM * NSPLIT * sizeof(int));
    float* out = (float*)d_out;

    build_tables<<<(T_DIM * NSPLIT + 255) / 256, 256, 0, stream>>>(masks, idx, val);

    const int grid = (B_DIM + BPB - 1) / BPB;   // 1639
    forest_kernel<<<grid, BLOCK, 0, stream>>>(x, pi, idx, val, out);
}

// Round 2
// 94.107 us; speedup vs baseline: 1.3258x; 1.3258x over previous
//
#include <hip/hip_runtime.h>

#define B_DIM   16384
#define T_DIM   50
#define F_DIM   128
#define NSPLIT  63
#define LEAVES  64
#define DEPTHM1 6
#define PROB_SZ (B_DIM * T_DIM * 2)

#define BLOCK   512           // 8 waves, each wave owns one b
#define WAVES   8
#define CHUNK   16            // leaves per transpose chunk
#define NCHUNK  (LEAVES / CHUNK)

// Kernel 1: extract (feature index, mask value) per (t, n) from one-hot masks.
// Packed as float2: x = bitcast(index), y = value.
__global__ void build_tables(const float* __restrict__ masks,
                             float2* __restrict__ tbl) {
    int k = blockIdx.x * blockDim.x + threadIdx.x;
    if (k >= T_DIM * NSPLIT) return;
    int t = k / NSPLIT, n = k % NSPLIT;
    int fi = 0; float fv = 0.f;
    for (int f = 0; f < F_DIM; ++f) {
        float m = masks[(t * F_DIM + f) * NSPLIT + n];
        if (m != 0.f) { fi = f; fv = m; }
    }
    tbl[k] = make_float2(__int_as_float(fi), fv);
}

__global__ __launch_bounds__(BLOCK, 4)
void forest_kernel(const float* __restrict__ x, const float* __restrict__ pi,
                   const float2* __restrict__ tbl, float* __restrict__ out) {
    __shared__ float2 tbl_l[T_DIM * NSPLIT];      // 25.2 KB
    __shared__ float  xs[WAVES * F_DIM];          //  4.0 KB
    __shared__ float  tile[WAVES][CHUNK * T_DIM]; // 25.6 KB  (per-wave transpose tile)

    const int tid = threadIdx.x;
    const int b0  = blockIdx.x * WAVES;

    for (int i = tid; i < T_DIM * NSPLIT; i += BLOCK) tbl_l[i] = tbl[i];
    for (int i = tid; i < WAVES * F_DIM; i += BLOCK)  xs[i] = x[b0 * F_DIM + i];
    __syncthreads();

    const int w    = tid >> 6;       // wave id = b sub-index
    const int lane = tid & 63;
    const int b    = b0 + w;
    const int t    = lane;           // lanes 50..63 idle during compute

    float mu[LEAVES];
#pragma unroll
    for (int l = 0; l < LEAVES; ++l) mu[l] = 0.f;

    if (t < T_DIM) {
        const float2* tt = &tbl_l[t * NSPLIT];
        const float*  xw = &xs[w * F_DIM];

        mu[0] = 1.f;
        int begin = 0;
#pragma unroll
        for (int level = 0; level < DEPTHM1; ++level) {
            const int width = 1 << level;
#pragma unroll
            for (int i = width - 1; i >= 0; --i) {
                float2 e  = tt[begin + i];
                float  xv = xw[__float_as_int(e.x)] * e.y;
                float  d  = 1.f / (1.f + __expf(-xv));
                float  m  = mu[i];
                mu[2 * i]     = m * d;
                mu[2 * i + 1] = m * (1.f - d);
            }
            begin += width;
        }

        // prob[b,t,s] = sum_l mu[l] * pi[t,l,s]   (pi row L1-resident, 512 B/t)
        const float4* pr = (const float4*)(pi + t * (LEAVES * 2));
        float p0 = 0.f, p1 = 0.f;
#pragma unroll
        for (int l2 = 0; l2 < LEAVES / 2; ++l2) {
            float4 q = pr[l2];
            p0 += mu[2 * l2] * q.x + mu[2 * l2 + 1] * q.z;
            p1 += mu[2 * l2] * q.y + mu[2 * l2 + 1] * q.w;
        }
        ((float2*)out)[b * T_DIM + t] = make_float2(p0, p1);
    }

    // probs[b,l,t]: per-wave LDS transpose -> contiguous float4 stores.
    float* tw   = tile[w];
    float* dstb = out + PROB_SZ + (size_t)b * (LEAVES * T_DIM);

#pragma unroll
    for (int c = 0; c < NCHUNK; ++c) {
        if (t < T_DIM) {
#pragma unroll
            for (int j = 0; j < CHUNK; ++j)
                tw[j * T_DIM + t] = mu[c * CHUNK + j];
        }
        __asm__ volatile("s_waitcnt lgkmcnt(0)" ::: "memory");

        float* dst = dstb + c * (CHUNK * T_DIM);   // 800 floats, contiguous
#pragma unroll
        for (int it = 0; it < 3; ++it) {
            int i4 = lane + it * 64;
            ((float4*)dst)[i4] = ((const float4*)tw)[i4];
        }
        if (lane < 8) {
            int i4 = lane + 192;
            ((float4*)dst)[i4] = ((const float4*)tw)[i4];
        }
    }
}

extern "C" void kernel_launch(void* const* d_in, const int* in_sizes, int n_in,
                              void* d_out, int out_size, void* d_ws, size_t ws_size,
                              hipStream_t stream) {
    const float* x     = (const float*)d_in[0];
    const float* masks = (const float*)d_in[1];
    const float* pi    = (const float*)d_in[2];

    float2* tbl = (float2*)d_ws;
    float*  out = (float*)d_out;

    build_tables<<<(T_DIM * NSPLIT + 255) / 256, 256, 0, stream>>>(masks, tbl);

    const int grid = B_DIM / WAVES;   // 2048
    forest_kernel<<<grid, BLOCK, 0, stream>>>(x, pi, tbl, out);
}

// Round 3
// 93.966 us; speedup vs baseline: 1.3278x; 1.0015x over previous
//
#include <hip/hip_runtime.h>

#define B_DIM   16384
#define T_DIM   50
#define F_DIM   128
#define NSPLIT  63
#define LEAVES  64
#define DEPTHM1 6
#define PROB_SZ (B_DIM * T_DIM * 2)

#define BLOCK   512           // 8 waves, each wave owns one b
#define WAVES   8
#define CHUNK   8             // leaves per transpose chunk
#define NCHUNK  (LEAVES / CHUNK)

// Kernel 1: extract (feature index, mask value) per (t, n) from one-hot masks.
__global__ void build_tables(const float* __restrict__ masks,
                             float2* __restrict__ tbl) {
    int k = blockIdx.x * blockDim.x + threadIdx.x;
    if (k >= T_DIM * NSPLIT) return;
    int t = k / NSPLIT, n = k % NSPLIT;
    int fi = 0; float fv = 0.f;
    for (int f = 0; f < F_DIM; ++f) {
        float m = masks[(t * F_DIM + f) * NSPLIT + n];
        if (m != 0.f) { fi = f; fv = m; }
    }
    tbl[k] = make_float2(__int_as_float(fi), fv);
}

__global__ __launch_bounds__(BLOCK, 6)
void forest_kernel(const float* __restrict__ x, const float* __restrict__ pi,
                   const float2* __restrict__ tbl, float* __restrict__ out) {
    __shared__ float2 tbl_l[T_DIM * NSPLIT];       // 25.2 KB
    __shared__ float  xs[WAVES * F_DIM];           //  4.0 KB
    __shared__ float  tile[WAVES][CHUNK * T_DIM];  // 12.8 KB
    // total 42.1 KB -> 3 blocks/CU (24 waves)

    const int tid = threadIdx.x;
    const int b0  = blockIdx.x * WAVES;

    for (int i = tid; i < T_DIM * NSPLIT; i += BLOCK) tbl_l[i] = tbl[i];
    for (int i = tid; i < WAVES * F_DIM; i += BLOCK)  xs[i] = x[b0 * F_DIM + i];
    __syncthreads();

    const int w    = tid >> 6;       // wave id = b sub-index
    const int lane = tid & 63;
    const int b    = b0 + w;
    const int t    = lane;           // lanes 50..63 idle during compute

    float mu[LEAVES];
#pragma unroll
    for (int l = 0; l < LEAVES; ++l) mu[l] = 0.f;

    if (t < T_DIM) {
        const float2* tt = &tbl_l[t * NSPLIT];
        const float*  xw = &xs[w * F_DIM];

        mu[0] = 1.f;
        int begin = 0;
#pragma unroll
        for (int level = 0; level < DEPTHM1; ++level) {
            const int width = 1 << level;
#pragma unroll
            for (int i = width - 1; i >= 0; --i) {
                float2 e  = tt[begin + i];
                float  xv = xw[__float_as_int(e.x)] * e.y;
                float  d  = 1.f / (1.f + __expf(-xv));
                float  m  = mu[i];
                mu[2 * i]     = m * d;
                mu[2 * i + 1] = m * (1.f - d);
            }
            begin += width;
        }
    }

    // Store phase: per-wave LDS transpose -> contiguous float4 stores.
    // pi-reduction folded in per chunk to fill store-wait latency.
    float* tw   = tile[w];
    float* dstb = out + PROB_SZ + (size_t)b * (LEAVES * T_DIM);
    float  p0 = 0.f, p1 = 0.f;

#pragma unroll
    for (int c = 0; c < NCHUNK; ++c) {
        if (t < T_DIM) {
#pragma unroll
            for (int j = 0; j < CHUNK; ++j)
                tw[j * T_DIM + t] = mu[c * CHUNK + j];

            // pi[t, l, s] for l in [8c, 8c+8): 16 consecutive floats
            const float4* pr = (const float4*)(pi + t * (LEAVES * 2) + c * (CHUNK * 2));
#pragma unroll
            for (int q4 = 0; q4 < CHUNK / 2; ++q4) {
                float4 q = pr[q4];
                int l = c * CHUNK + q4 * 2;
                p0 += mu[l] * q.x + mu[l + 1] * q.z;
                p1 += mu[l] * q.y + mu[l + 1] * q.w;
            }
        }

        // 400 floats = 100 float4 per chunk (compiler inserts minimal lgkmcnt)
        float* dst = dstb + c * (CHUNK * T_DIM);
        ((float4*)dst)[lane] = ((const float4*)tw)[lane];
        if (lane < 36) {
            int i4 = lane + 64;
            ((float4*)dst)[i4] = ((const float4*)tw)[i4];
        }
    }

    if (t < T_DIM)
        ((float2*)out)[b * T_DIM + t] = make_float2(p0, p1);
}

extern "C" void kernel_launch(void* const* d_in, const int* in_sizes, int n_in,
                              void* d_out, int out_size, void* d_ws, size_t ws_size,
                              hipStream_t stream) {
    const float* x     = (const float*)d_in[0];
    const float* masks = (const float*)d_in[1];
    const float* pi    = (const float*)d_in[2];

    float2* tbl = (float2*)d_ws;
    float*  out = (float*)d_out;

    build_tables<<<(T_DIM * NSPLIT + 255) / 256, 256, 0, stream>>>(masks, tbl);

    const int grid = B_DIM / WAVES;   // 2048
    forest_kernel<<<grid, BLOCK, 0, stream>>>(x, pi, tbl, out);
}

// Round 5
// 88.191 us; speedup vs baseline: 1.4147x; 1.0655x over previous
//
#include <hip/hip_runtime.h>

#define B_DIM   16384
#define T_DIM   50
#define F_DIM   128
#define NSPLIT  63
#define LEAVES  64
#define DEPTHM1 6
#define PROB_SZ (B_DIM * T_DIM * 2)

#define BLOCK   512           // 8 waves, each wave owns one b
#define WAVES   8
#define CHUNK   8             // leaves per transpose chunk
#define NCHUNK  (LEAVES / CHUNK)

typedef float vf4 __attribute__((ext_vector_type(4)));   // clang-native vec4

// Kernel 1: block per t; stage masks[t] (32.2 KB) coalesced into LDS, then
// lane n scans f. ~2 us vs ~20+ us for the strided-scalar version.
__global__ __launch_bounds__(256)
void build_tables(const float* __restrict__ masks, float2* __restrict__ tbl) {
    __shared__ float m_l[F_DIM * NSPLIT];   // 32.2 KB
    const int t = blockIdx.x;
    const float* src = masks + (size_t)t * (F_DIM * NSPLIT);
    for (int i = threadIdx.x; i < F_DIM * NSPLIT; i += 256) m_l[i] = src[i];
    __syncthreads();
    const int n = threadIdx.x;
    if (n < NSPLIT) {
        int fi = 0; float fv = 0.f;
        for (int f = 0; f < F_DIM; ++f) {
            float v = m_l[f * NSPLIT + n];
            if (v != 0.f) { fi = f; fv = v; }
        }
        tbl[t * NSPLIT + n] = make_float2(__int_as_float(fi), fv);
    }
}

__global__ __launch_bounds__(BLOCK, 4)
void forest_kernel(const float* __restrict__ x, const float* __restrict__ pi,
                   const float2* __restrict__ tbl, float* __restrict__ out) {
    __shared__ float2 tbl_l[T_DIM * NSPLIT];          // 25.2 KB
    __shared__ float  xs[WAVES * F_DIM];              //  4.0 KB
    __shared__ float  tile[WAVES][2][CHUNK * T_DIM];  // 25.6 KB (double-buffered)
    // total 54.8 KB -> 2 blocks/CU

    const int tid = threadIdx.x;
    const int b0  = blockIdx.x * WAVES;

    for (int i = tid; i < T_DIM * NSPLIT; i += BLOCK) tbl_l[i] = tbl[i];
    for (int i = tid; i < WAVES * F_DIM; i += BLOCK)  xs[i] = x[b0 * F_DIM + i];
    __syncthreads();

    const int w    = tid >> 6;
    const int lane = tid & 63;
    const int b    = b0 + w;
    const int t    = lane;            // lanes 50..63 idle during compute

    float mu[LEAVES];
#pragma unroll
    for (int l = 0; l < LEAVES; ++l) mu[l] = 0.f;

    float p0 = 0.f, p1 = 0.f;

    if (t < T_DIM) {
        const float2* tt = &tbl_l[t * NSPLIT];
        const float*  xw = &xs[w * F_DIM];

        mu[0] = 1.f;
        int begin = 0;
#pragma unroll
        for (int level = 0; level < DEPTHM1; ++level) {
            const int width = 1 << level;
#pragma unroll
            for (int i = width - 1; i >= 0; --i) {
                float2 e  = tt[begin + i];
                float  xv = xw[__float_as_int(e.x)] * e.y;
                float  d  = 1.f / (1.f + __expf(-xv));
                float  m  = mu[i];
                mu[2 * i]     = m * d;
                mu[2 * i + 1] = m * (1.f - d);
            }
            begin += width;
        }

        // prob[b,t,s] = sum_l mu[l] * pi[t,l,s] (pi rows L1/L2-resident)
        const float4* pr = (const float4*)(pi + t * (LEAVES * 2));
#pragma unroll
        for (int l2 = 0; l2 < LEAVES / 2; ++l2) {
            float4 q = pr[l2];
            p0 += mu[2 * l2] * q.x + mu[2 * l2 + 1] * q.z;
            p1 += mu[2 * l2] * q.y + mu[2 * l2 + 1] * q.w;
        }
        ((float2*)out)[b * T_DIM + t] = make_float2(p0, p1);
    }

    // Store phase: double-buffered per-wave LDS transpose -> contiguous
    // nontemporal float4 stores. Write chunk c+1 while storing chunk c.
    float* twA  = tile[w][0];
    float* twB  = tile[w][1];
    float* dstb = out + PROB_SZ + (size_t)b * (LEAVES * T_DIM);

#define WRITE_CHUNK(buf, c)                                        \
    if (t < T_DIM) {                                               \
        _Pragma("unroll")                                          \
        for (int j = 0; j < CHUNK; ++j)                            \
            (buf)[j * T_DIM + t] = mu[(c) * CHUNK + j];            \
    }

#define STORE_CHUNK(buf, c)                                        \
    {                                                              \
        float* dst = dstb + (c) * (CHUNK * T_DIM);                 \
        __builtin_nontemporal_store(((const vf4*)(buf))[lane],     \
                                    &((vf4*)dst)[lane]);           \
        if (lane < 36) {                                           \
            int i4 = lane + 64;                                    \
            __builtin_nontemporal_store(((const vf4*)(buf))[i4],   \
                                        &((vf4*)dst)[i4]);         \
        }                                                          \
    }

    WRITE_CHUNK(twA, 0)
#pragma unroll
    for (int c = 0; c < NCHUNK; c += 2) {
        if (c + 1 < NCHUNK) WRITE_CHUNK(twB, c + 1)
        STORE_CHUNK(twA, c)
        if (c + 2 < NCHUNK) WRITE_CHUNK(twA, c + 2)
        if (c + 1 < NCHUNK) STORE_CHUNK(twB, c + 1)
    }
#undef WRITE_CHUNK
#undef STORE_CHUNK
}

extern "C" void kernel_launch(void* const* d_in, const int* in_sizes, int n_in,
                              void* d_out, int out_size, void* d_ws, size_t ws_size,
                              hipStream_t stream) {
    const float* x     = (const float*)d_in[0];
    const float* masks = (const float*)d_in[1];
    const float* pi    = (const float*)d_in[2];

    float2* tbl = (float2*)d_ws;
    float*  out = (float*)d_out;

    build_tables<<<T_DIM, 256, 0, stream>>>(masks, tbl);

    const int grid = B_DIM / WAVES;   // 2048
    forest_kernel<<<grid, BLOCK, 0, stream>>>(x, pi, tbl, out);
}

// Round 6
// 80.779 us; speedup vs baseline: 1.5445x; 1.0918x over previous
//
#include <hip/hip_runtime.h>

#define B_DIM   16384
#define T_DIM   50
#define F_DIM   128
#define NSPLIT  63
#define LEAVES  64
#define DEPTHM1 6
#define PROB_SZ (B_DIM * T_DIM * 2)

#define WPB   4                    // waves per block
#define BLOCK (WPB * 64)           // 256
#define IT    2                    // b's per wave
#define GRID  (B_DIM / (WPB * IT)) // 2048

typedef float vf2 __attribute__((ext_vector_type(2)));

// Kernel 1: one-hot masks -> u16 feature index per (t, n).
// (mask values are exactly 1.0 by construction, so no value table needed)
__global__ __launch_bounds__(256)
void build_tables(const float* __restrict__ masks, unsigned short* __restrict__ idx) {
    __shared__ float m_l[F_DIM * NSPLIT];   // 32.2 KB
    const int t = blockIdx.x;
    const float* src = masks + (size_t)t * (F_DIM * NSPLIT);
    for (int i = threadIdx.x; i < F_DIM * NSPLIT; i += 256) m_l[i] = src[i];
    __syncthreads();
    const int n = threadIdx.x;
    if (n < NSPLIT) {
        int fi = 0;
        for (int f = 0; f < F_DIM; ++f)
            if (m_l[f * NSPLIT + n] != 0.f) fi = f;
        idx[t * NSPLIT + n] = (unsigned short)fi;
    }
}

__global__ __launch_bounds__(BLOCK, 4)
void forest_kernel(const float* __restrict__ x, const float* __restrict__ pi,
                   const unsigned short* __restrict__ tbl, float* __restrict__ out) {
    __shared__ unsigned short idx_l[T_DIM * NSPLIT];  // 6.3 KB
    __shared__ float xs[WPB][F_DIM];                  // 2.0 KB  (wave-private rows)

    const int tid = threadIdx.x;
    for (int i = tid; i < (T_DIM * NSPLIT) / 2; i += BLOCK)
        ((unsigned int*)idx_l)[i] = ((const unsigned int*)tbl)[i];
    __syncthreads();   // only block-wide barrier; waves free-run afterwards

    const int w    = tid >> 6;
    const int lane = tid & 63;
    const int t    = lane;                       // lanes 50..63 idle in compute
    const int bw0  = (blockIdx.x * WPB + w) * IT;
    float* xw = xs[w];

    // prologue: first x row -> regs (all 64 lanes, coalesced 512B)
    vf2 xreg = *(const vf2*)(x + (size_t)bw0 * F_DIM + 2 * lane);

    for (int it = 0; it < IT; ++it) {
        const int b = bw0 + it;

        // wave-private LDS write; DS ops are in-order vs previous iter's reads
        *(vf2*)(&xw[2 * lane]) = xreg;

        float mu[LEAVES];
        float p0 = 0.f, p1 = 0.f;

        if (t < T_DIM) {
            const unsigned short* tt = &idx_l[t * NSPLIT];
            mu[0] = 1.f;
            int begin = 0;
#pragma unroll
            for (int level = 0; level < DEPTHM1; ++level) {
                const int width = 1 << level;
#pragma unroll
                for (int i = width - 1; i >= 0; --i) {
                    const int k  = begin + i;
                    const int fi = (int)tt[k];               // ds_read_u16
                    float xv = xw[fi];                       // ds_read_b32 gather
                    float e  = __expf(-xv);                  // v_mul + v_exp
                    float d  = __builtin_amdgcn_rcpf(1.f + e); // v_add + v_rcp
                    float m  = mu[i];
                    mu[2 * i]     = m * d;
                    mu[2 * i + 1] = m - mu[2 * i];           // m*(1-d)
                }
                begin += width;
            }
        }

        // prefetch next x row while stores drain (independent of stores)
        if (it + 1 < IT)
            xreg = *(const vf2*)(x + (size_t)(b + 1) * F_DIM + 2 * lane);

        if (t < T_DIM) {
            // prob[b,t,:] = sum_l mu[l] * pi[t,l,:]   (pi row L1-resident)
            const float4* pr = (const float4*)(pi + t * (LEAVES * 2));
#pragma unroll
            for (int l2 = 0; l2 < LEAVES / 2; ++l2) {
                float4 q = pr[l2];
                p0 += mu[2 * l2] * q.x + mu[2 * l2 + 1] * q.z;
                p1 += mu[2 * l2] * q.y + mu[2 * l2 + 1] * q.w;
            }
            ((vf2*)out)[b * T_DIM + t] = (vf2){p0, p1};

            // probs[b,l,t]: lane=t -> each store inst covers a contiguous
            // 200B run; L2 merges runs across l (R0 verified exact WRITE_SIZE)
            float* dstb = out + PROB_SZ + (size_t)b * (LEAVES * T_DIM) + t;
#pragma unroll
            for (int l = 0; l < LEAVES; ++l)
                dstb[l * T_DIM] = mu[l];
        }
    }
}

extern "C" void kernel_launch(void* const* d_in, const int* in_sizes, int n_in,
                              void* d_out, int out_size, void* d_ws, size_t ws_size,
                              hipStream_t stream) {
    const float* x     = (const float*)d_in[0];
    const float* masks = (const float*)d_in[1];
    const float* pi    = (const float*)d_in[2];

    unsigned short* tbl = (unsigned short*)d_ws;
    float* out = (float*)d_out;

    build_tables<<<T_DIM, 256, 0, stream>>>(masks, tbl);
    forest_kernel<<<GRID, BLOCK, 0, stream>>>(x, pi, tbl, out);
}

// Round 7
// 59.589 us; speedup vs baseline: 2.0938x; 1.3556x over previous
//
#include <hip/hip_runtime.h>

#define B_DIM   16384
#define T_DIM   50
#define F_DIM   128
#define NSPLIT  63
#define LEAVES  64
#define DEPTHM1 6
#define PROB_SZ (B_DIM * T_DIM * 2)

#define WPB   4                    // waves per block
#define BLOCK (WPB * 64)           // 256
#define IT    2                    // b's per wave
#define GRID  (B_DIM / (WPB * IT)) // 2048

typedef float vf2 __attribute__((ext_vector_type(2)));

// Kernel 1: one-hot masks -> u16 feature index per (t, n).
__global__ __launch_bounds__(256)
void build_tables(const float* __restrict__ masks, unsigned short* __restrict__ idx) {
    __shared__ float m_l[F_DIM * NSPLIT];   // 32.2 KB
    const int t = blockIdx.x;
    const float* src = masks + (size_t)t * (F_DIM * NSPLIT);
    for (int i = threadIdx.x; i < F_DIM * NSPLIT; i += 256) m_l[i] = src[i];
    __syncthreads();
    const int n = threadIdx.x;
    if (n < NSPLIT) {
        int fi = 0;
        for (int f = 0; f < F_DIM; ++f)
            if (m_l[f * NSPLIT + n] != 0.f) fi = f;
        idx[t * NSPLIT + n] = (unsigned short)fi;
    }
}

__global__ __launch_bounds__(BLOCK, 4)
void forest_kernel(const float* __restrict__ x, const float* __restrict__ pi,
                   const unsigned short* __restrict__ tbl, float* __restrict__ out) {
    __shared__ unsigned short idx_l[T_DIM * NSPLIT];  //  6.3 KB
    __shared__ float xs[WPB][F_DIM];                  //  2.0 KB (wave-private rows)
    __shared__ vf2   pi_p[LEAVES * T_DIM];            // 25.6 KB: [l][t] = (pi[t,l,0], pi[t,l,1])

    const int tid = threadIdx.x;
    for (int i = tid; i < (T_DIM * NSPLIT) / 2; i += BLOCK)
        ((unsigned int*)idx_l)[i] = ((const unsigned int*)tbl)[i];
    // pi transpose-stage: global float2 index i = t*64 + l  ->  LDS [l*50 + t]
    for (int i = tid; i < T_DIM * LEAVES; i += BLOCK) {
        int t2 = i >> 6, l2 = i & 63;
        vf2 q = ((const vf2*)pi)[i];
        pi_p[l2 * T_DIM + t2] = q;
    }
    __syncthreads();   // only block-wide barrier; waves free-run afterwards

    const int w    = tid >> 6;
    const int lane = tid & 63;
    const int t    = lane;                       // lanes 50..63 idle in compute
    const int bw0  = (blockIdx.x * WPB + w) * IT;
    float* xw = xs[w];

    // prologue: first x row -> regs (all 64 lanes, coalesced 512B)
    vf2 xreg = *(const vf2*)(x + (size_t)bw0 * F_DIM + 2 * lane);

    for (int it = 0; it < IT; ++it) {
        const int b = bw0 + it;

        // wave-private LDS write; DS ops are in-order vs previous iter's reads
        *(vf2*)(&xw[2 * lane]) = xreg;

        float mu[LEAVES];
        float p0 = 0.f, p1 = 0.f;

        if (t < T_DIM) {
            const unsigned short* tt = &idx_l[t * NSPLIT];
            mu[0] = 1.f;
            int begin = 0;
#pragma unroll
            for (int level = 0; level < DEPTHM1; ++level) {
                const int width = 1 << level;
#pragma unroll
                for (int i = width - 1; i >= 0; --i) {
                    const int fi = (int)tt[begin + i];         // ds_read_u16, 2-way
                    float xv = xw[fi];                         // ds_read_b32 gather
                    float e  = __expf(-xv);
                    float d  = __builtin_amdgcn_rcpf(1.f + e);
                    float m  = mu[i];
                    mu[2 * i]     = m * d;
                    mu[2 * i + 1] = m - mu[2 * i];             // m*(1-d)
                }
                begin += width;
            }
        }

        // prefetch next x row while stores drain (independent of stores)
        if (it + 1 < IT)
            xreg = *(const vf2*)(x + (size_t)(b + 1) * F_DIM + 2 * lane);

        if (t < T_DIM) {
            // prob[b,t,:] = sum_l mu[l] * pi_p[l][t] — conflict-free ds_read_b64
            const vf2* pp = &pi_p[t];
#pragma unroll
            for (int l = 0; l < LEAVES; ++l) {
                vf2 q = pp[l * T_DIM];
                p0 += mu[l] * q.x;
                p1 += mu[l] * q.y;
            }
            ((vf2*)out)[b * T_DIM + t] = (vf2){p0, p1};

            // probs[b,l,t]: lane=t -> contiguous 200B run per store; L2 merges
            float* dstb = out + PROB_SZ + (size_t)b * (LEAVES * T_DIM) + t;
#pragma unroll
            for (int l = 0; l < LEAVES; ++l)
                dstb[l * T_DIM] = mu[l];
        }
    }
}

extern "C" void kernel_launch(void* const* d_in, const int* in_sizes, int n_in,
                              void* d_out, int out_size, void* d_ws, size_t ws_size,
                              hipStream_t stream) {
    const float* x     = (const float*)d_in[0];
    const float* masks = (const float*)d_in[1];
    const float* pi    = (const float*)d_in[2];

    unsigned short* tbl = (unsigned short*)d_ws;
    float* out = (float*)d_out;

    build_tables<<<T_DIM, 256, 0, stream>>>(masks, tbl);
    forest_kernel<<<GRID, BLOCK, 0, stream>>>(x, pi, tbl, out);
}

// Round 8
// 52.185 us; speedup vs baseline: 2.3909x; 1.1419x over previous
//
#include <hip/hip_runtime.h>

#define B_DIM   16384
#define T_DIM   50
#define F_DIM   128
#define NSPLIT  63
#define LEAVES  64
#define DEPTHM1 6
#define PROB_SZ (B_DIM * T_DIM * 2)

#define WPB   4                    // waves per block
#define BLOCK (WPB * 64)           // 256
#define IT    2                    // b's per wave
#define GRID  (B_DIM / (WPB * IT)) // 2048

typedef float vf2 __attribute__((ext_vector_type(2)));

// Kernel 1: one-hot masks -> u8 feature index per (t, n). (F=128 fits u8;
// mask values are exactly 1.0 by construction.)
__global__ __launch_bounds__(256)
void build_tables(const float* __restrict__ masks, unsigned char* __restrict__ idx) {
    __shared__ float m_l[F_DIM * NSPLIT];   // 32.2 KB
    const int t = blockIdx.x;
    const float* src = masks + (size_t)t * (F_DIM * NSPLIT);
    for (int i = threadIdx.x; i < F_DIM * NSPLIT; i += 256) m_l[i] = src[i];
    __syncthreads();
    const int n = threadIdx.x;
    if (n < NSPLIT) {
        int fi = 0;
        for (int f = 0; f < F_DIM; ++f)
            if (m_l[f * NSPLIT + n] != 0.f) fi = f;
        idx[t * NSPLIT + n] = (unsigned char)fi;
    }
}

__global__ __launch_bounds__(BLOCK, 4)
void forest_kernel(const float* __restrict__ x, const float* __restrict__ pi,
                   const unsigned char* __restrict__ tbl, float* __restrict__ out) {
    __shared__ unsigned char idx_l[T_DIM * NSPLIT + 2];  // 3.15 KB
    __shared__ float xs[WPB][F_DIM];                     // 2.0 KB (wave-private rows)
    __shared__ vf2   pi_p[LEAVES * T_DIM];               // 25.6 KB: [l][t]=(pi[t,l,0],pi[t,l,1])
    // total 30.8 KB -> 5 blocks/CU (20 waves)

    const int tid = threadIdx.x;
    for (int i = tid; i < (T_DIM * NSPLIT + 3) / 4; i += BLOCK)
        ((unsigned int*)idx_l)[i] = ((const unsigned int*)tbl)[i];
    // pi transpose-stage: global float2 index i = t*64 + l -> LDS [l*50 + t]
    for (int i = tid; i < T_DIM * LEAVES; i += BLOCK) {
        int t2 = i >> 6, l2 = i & 63;
        vf2 q = ((const vf2*)pi)[i];
        pi_p[l2 * T_DIM + t2] = q;
    }
    __syncthreads();   // only block-wide barrier; waves free-run afterwards

    const int w    = tid >> 6;
    const int lane = tid & 63;
    const int t    = lane;                       // lanes 50..63 idle in compute
    const int bw0  = (blockIdx.x * WPB + w) * IT;
    float* xw = xs[w];

    // prologue: first x row -> regs (all 64 lanes, coalesced 512B)
    vf2 xreg = *(const vf2*)(x + (size_t)bw0 * F_DIM + 2 * lane);

    for (int it = 0; it < IT; ++it) {
        const int b = bw0 + it;

        // wave-private LDS write; DS ops are in-order vs previous iter's reads
        *(vf2*)(&xw[2 * lane]) = xreg;

        float mu[LEAVES / 2];       // only levels 0..4 materialize (32 regs)
        float p0 = 0.f, p1 = 0.f;
        float* dstb = out + PROB_SZ + (size_t)b * (LEAVES * T_DIM) + t;

        if (t < T_DIM) {
            const unsigned char* tt = &idx_l[t * NSPLIT];
            const vf2* pp = &pi_p[t];

            mu[0] = 1.f;
            int begin = 0;
            // levels 0..4: pure compute, builds mu[0..31]
#pragma unroll
            for (int level = 0; level < DEPTHM1 - 1; ++level) {
                const int width = 1 << level;
#pragma unroll
                for (int i = width - 1; i >= 0; --i) {
                    const int fi = (int)tt[begin + i];          // ds_read_u8
                    float xv = xw[fi];                          // ds_read_b32 gather
                    float e  = __expf(-xv);
                    float d  = __builtin_amdgcn_rcpf(1.f + e);
                    float m  = mu[i];
                    mu[2 * i]     = m * d;
                    mu[2 * i + 1] = m - mu[2 * i];
                }
                begin += width;
            }
            // level 5 fused with probs-store + pi-reduction: spreads the 64
            // stores across the whole tail of the iteration (anti-convoy)
#pragma unroll
            for (int i = 31; i >= 0; --i) {
                const int fi = (int)tt[31 + i];
                float xv = xw[fi];
                float e  = __expf(-xv);
                float d  = __builtin_amdgcn_rcpf(1.f + e);
                float m  = mu[i];
                float a  = m * d;
                float c2 = m - a;
                dstb[(2 * i)     * T_DIM] = a;     // contiguous 200B run/inst
                dstb[(2 * i + 1) * T_DIM] = c2;
                vf2 q0 = pp[(2 * i)     * T_DIM];  // conflict-free ds_read_b64
                vf2 q1 = pp[(2 * i + 1) * T_DIM];
                p0 += a * q0.x + c2 * q1.x;
                p1 += a * q0.y + c2 * q1.y;
            }
        }

        // prefetch next x row while stores drain
        if (it + 1 < IT)
            xreg = *(const vf2*)(x + (size_t)(b + 1) * F_DIM + 2 * lane);

        if (t < T_DIM)
            ((vf2*)out)[b * T_DIM + t] = (vf2){p0, p1};
    }
}

extern "C" void kernel_launch(void* const* d_in, const int* in_sizes, int n_in,
                              void* d_out, int out_size, void* d_ws, size_t ws_size,
                              hipStream_t stream) {
    const float* x     = (const float*)d_in[0];
    const float* masks = (const float*)d_in[1];
    const float* pi    = (const float*)d_in[2];

    unsigned char* tbl = (unsigned char*)d_ws;
    float* out = (float*)d_out;

    build_tables<<<T_DIM, 256, 0, stream>>>(masks, tbl);
    forest_kernel<<<GRID, BLOCK, 0, stream>>>(x, pi, tbl, out);
}